// Round 14
// baseline (594.235 us; speedup 1.0000x reference)
//
#include <hip/hip_runtime.h>
#include <hip/hip_cooperative_groups.h>
#include <hip/hip_bf16.h>
#include <stdint.h>

typedef int i32x4 __attribute__((ext_vector_type(4)));

#define QMAX 127.0f
#define NB_QA 1024   // cooperative grid: 4 blocks/CU x 256 CU

// ------------- fused absmax + quantize, ONE cooperative kernel -------------
// pass1: per-block absmax partials for x and w -> grid.sync ->
// all-blocks reduce partials (8KB, L2-broadcast) -> pass2 quantize both.
// q = clip(rint(v/scale), -128, 127), scale = amax/127 (0 -> 1): bit-exact
// vs jnp.round (rintf = half-even), IEEE divide identical to reference.
__global__ __launch_bounds__(256, 4) void k_quantabs(
    const float4* __restrict__ x, unsigned* __restrict__ qx, int n4x,
    const float4* __restrict__ w, unsigned* __restrict__ qw, int n4w,
    float* __restrict__ partials, unsigned* __restrict__ scales)
{
  const int NB  = gridDim.x;
  const int tid = blockIdx.x * blockDim.x + threadIdx.x;
  const int T   = NB * blockDim.x;

  // ---- pass 1: thread-local absmax, 4 independent load streams ----
  float mx0 = 0.f, mx1 = 0.f, mx2 = 0.f, mx3 = 0.f;
  int i = tid;
  for (; i + 3 * T < n4x; i += 4 * T) {
    float4 v0 = x[i], v1 = x[i + T], v2 = x[i + 2 * T], v3 = x[i + 3 * T];
    mx0 = fmaxf(mx0, fmaxf(fmaxf(fabsf(v0.x), fabsf(v0.y)), fmaxf(fabsf(v0.z), fabsf(v0.w))));
    mx1 = fmaxf(mx1, fmaxf(fmaxf(fabsf(v1.x), fabsf(v1.y)), fmaxf(fabsf(v1.z), fabsf(v1.w))));
    mx2 = fmaxf(mx2, fmaxf(fmaxf(fabsf(v2.x), fabsf(v2.y)), fmaxf(fabsf(v2.z), fabsf(v2.w))));
    mx3 = fmaxf(mx3, fmaxf(fmaxf(fabsf(v3.x), fabsf(v3.y)), fmaxf(fabsf(v3.z), fabsf(v3.w))));
  }
  for (; i < n4x; i += T) {
    float4 v = x[i];
    mx0 = fmaxf(mx0, fmaxf(fmaxf(fabsf(v.x), fabsf(v.y)), fmaxf(fabsf(v.z), fabsf(v.w))));
  }
  float mx = fmaxf(fmaxf(mx0, mx1), fmaxf(mx2, mx3));

  float mw0 = 0.f, mw1 = 0.f, mw2 = 0.f, mw3 = 0.f;
  i = tid;
  for (; i + 3 * T < n4w; i += 4 * T) {
    float4 v0 = w[i], v1 = w[i + T], v2 = w[i + 2 * T], v3 = w[i + 3 * T];
    mw0 = fmaxf(mw0, fmaxf(fmaxf(fabsf(v0.x), fabsf(v0.y)), fmaxf(fabsf(v0.z), fabsf(v0.w))));
    mw1 = fmaxf(mw1, fmaxf(fmaxf(fabsf(v1.x), fabsf(v1.y)), fmaxf(fabsf(v1.z), fabsf(v1.w))));
    mw2 = fmaxf(mw2, fmaxf(fmaxf(fabsf(v2.x), fabsf(v2.y)), fmaxf(fabsf(v2.z), fabsf(v2.w))));
    mw3 = fmaxf(mw3, fmaxf(fmaxf(fabsf(v3.x), fabsf(v3.y)), fmaxf(fabsf(v3.z), fabsf(v3.w))));
  }
  for (; i < n4w; i += T) {
    float4 v = w[i];
    mw0 = fmaxf(mw0, fmaxf(fmaxf(fabsf(v.x), fabsf(v.y)), fmaxf(fabsf(v.z), fabsf(v.w))));
  }
  float mw = fmaxf(fmaxf(mw0, mw1), fmaxf(mw2, mw3));

#pragma unroll
  for (int off = 32; off > 0; off >>= 1) {
    mx = fmaxf(mx, __shfl_xor(mx, off, 64));
    mw = fmaxf(mw, __shfl_xor(mw, off, 64));
  }
  __shared__ float r1[8];
  if ((threadIdx.x & 63) == 0) {
    int wv = threadIdx.x >> 6;
    r1[wv] = mx; r1[4 + wv] = mw;
  }
  __syncthreads();
  if (threadIdx.x == 0) {
    partials[blockIdx.x]      = fmaxf(fmaxf(r1[0], r1[1]), fmaxf(r1[2], r1[3]));
    partials[NB + blockIdx.x] = fmaxf(fmaxf(r1[4], r1[5]), fmaxf(r1[6], r1[7]));
  }

  cooperative_groups::this_grid().sync();

  // ---- all blocks: reduce the 2*NB partials (tiny, L2-broadcast) ----
  float px = 0.f, pw = 0.f;
  for (int j = threadIdx.x; j < NB; j += blockDim.x) {
    px = fmaxf(px, partials[j]);
    pw = fmaxf(pw, partials[NB + j]);
  }
#pragma unroll
  for (int off = 32; off > 0; off >>= 1) {
    px = fmaxf(px, __shfl_xor(px, off, 64));
    pw = fmaxf(pw, __shfl_xor(pw, off, 64));
  }
  __shared__ float r2[8];
  if ((threadIdx.x & 63) == 0) {
    int wv = threadIdx.x >> 6;
    r2[wv] = px; r2[4 + wv] = pw;
  }
  __syncthreads();
  const float amax_x = fmaxf(fmaxf(r2[0], r2[1]), fmaxf(r2[2], r2[3]));
  const float amax_w = fmaxf(fmaxf(r2[4], r2[5]), fmaxf(r2[6], r2[7]));
  if (tid == 0) {
    scales[0] = __float_as_uint(amax_x);
    scales[1] = __float_as_uint(amax_w);
  }
  float sclx = amax_x / QMAX; if (sclx == 0.f) sclx = 1.f;
  float sclw = amax_w / QMAX; if (sclw == 0.f) sclw = 1.f;

  // ---- pass 2: quantize (x,w L3-hot from pass 1) ----
  for (i = tid; i < n4x; i += T) {
    float4 v = x[i];
    int q0 = (int)fminf(fmaxf(rintf(v.x / sclx), -128.f), 127.f);
    int q1 = (int)fminf(fmaxf(rintf(v.y / sclx), -128.f), 127.f);
    int q2 = (int)fminf(fmaxf(rintf(v.z / sclx), -128.f), 127.f);
    int q3 = (int)fminf(fmaxf(rintf(v.w / sclx), -128.f), 127.f);
    qx[i] = (unsigned)(q0 & 255) | ((unsigned)(q1 & 255) << 8) |
            ((unsigned)(q2 & 255) << 16) | ((unsigned)(q3 & 255) << 24);
  }
  for (i = tid; i < n4w; i += T) {
    float4 v = w[i];
    int q0 = (int)fminf(fmaxf(rintf(v.x / sclw), -128.f), 127.f);
    int q1 = (int)fminf(fmaxf(rintf(v.y / sclw), -128.f), 127.f);
    int q2 = (int)fminf(fmaxf(rintf(v.z / sclw), -128.f), 127.f);
    int q3 = (int)fminf(fmaxf(rintf(v.w / sclw), -128.f), 127.f);
    qw[i] = (unsigned)(q0 & 255) | ((unsigned)(q1 & 255) << 8) |
            ((unsigned)(q2 & 255) << 16) | ((unsigned)(q3 & 255) << 24);
  }
}

// ---------------- int8 GEMM, B^T layout (m97 structure, VERIFIED r7) -------
// C[m][n] = s * sum_k A[m][k]*B[n][k] + bias[n], A/B int8, acc int32 (exact).
// 128x128 tile, BK=64 i8, 4 waves, 16x16x64 i8 MFMA, global_load_lds w=16,
// linear LDS, XCD swizzle. r10: reverted nontemporal stores (r9: WRITE
// inflated 131->176MB, FETCH barely moved -> theory falsified).
#define BM 128
#define BN 128
#define BK 64

__global__ __launch_bounds__(256) void k_gemm(
    const signed char* __restrict__ Aq, const signed char* __restrict__ Bq,
    const float* __restrict__ bias, const unsigned* __restrict__ slots,
    float* __restrict__ C, int M, int N, int K)
{
  __shared__ alignas(16) signed char As[BM][BK];   // 8 KB
  __shared__ alignas(16) signed char Bs[BN][BK];   // 8 KB

  const int tid  = threadIdx.x;
  const int lane = tid & 63;
  const int wave = tid >> 6;
  const int wm = wave >> 1, wn = wave & 1;

  const int nbx = N / BN;
  const int nwg = gridDim.x;
  int bx = blockIdx.x;
  if ((nwg & 7) == 0) {                 // bijective XCD swizzle (nwg%8==0)
    int cpx = nwg >> 3;
    bx = (bx & 7) * cpx + (bx >> 3);
  }
  const int brow = (bx / nbx) * BM;
  const int bcol = (bx % nbx) * BN;

  const int lrow = lane & 15;           // fragment row (A) / col (B)
  const int lkob = (lane >> 4) * 16;    // k-byte-offset of this lane-group

  const signed char* Ag = Aq + (size_t)brow * K;
  const signed char* Bg = Bq + (size_t)bcol * K;

  i32x4 acc[4][4] = {};                 // int32 accum, bit-exact

  for (int k0 = 0; k0 < K; k0 += BK) {
#pragma unroll
    for (int c = 0; c < 2; ++c) {
      int lin = c * 256 + tid;          // 16B units; 4 per 64B row
      int row = lin >> 2, unit = lin & 3;
      __builtin_amdgcn_global_load_lds(
          (__attribute__((address_space(1))) void*)(Ag + (size_t)row * K + k0 + unit * 16),
          (__attribute__((address_space(3))) void*)((signed char*)&As[0][0] + lin * 16),
          16, 0, 0);
    }
#pragma unroll
    for (int c = 0; c < 2; ++c) {
      int lin = c * 256 + tid;
      int row = lin >> 2, unit = lin & 3;
      __builtin_amdgcn_global_load_lds(
          (__attribute__((address_space(1))) void*)(Bg + (size_t)row * K + k0 + unit * 16),
          (__attribute__((address_space(3))) void*)((signed char*)&Bs[0][0] + lin * 16),
          16, 0, 0);
    }
    __syncthreads();   // compiler drains vmcnt before s_barrier

    i32x4 af[4], bfr[4];
#pragma unroll
    for (int mi = 0; mi < 4; ++mi)
      af[mi] = *(const i32x4*)&As[wm * 64 + mi * 16 + lrow][lkob];
#pragma unroll
    for (int ni = 0; ni < 4; ++ni)
      bfr[ni] = *(const i32x4*)&Bs[wn * 64 + ni * 16 + lrow][lkob];
#pragma unroll
    for (int mi = 0; mi < 4; ++mi)
#pragma unroll
      for (int ni = 0; ni < 4; ++ni)
        acc[mi][ni] = __builtin_amdgcn_mfma_i32_16x16x64_i8(
            af[mi], bfr[ni], acc[mi][ni], 0, 0, 0);

    __syncthreads();
  }

  // epilogue: dequant scale + bias. |dot| <= 128*128*4096 < 2^31 (no ovf).
  float sx = __uint_as_float(slots[0]) / QMAX; if (sx == 0.f) sx = 1.f;
  float sw = __uint_as_float(slots[1]) / QMAX; if (sw == 0.f) sw = 1.f;
  const float s = sx * sw;

  // C/D layout dtype-independent (m121-m128): col=lane&15, row=(lane>>4)*4+reg
#pragma unroll
  for (int mi = 0; mi < 4; ++mi)
#pragma unroll
    for (int ni = 0; ni < 4; ++ni) {
      const int n = bcol + wn * 64 + ni * 16 + lrow;
      const float b = bias[n];
#pragma unroll
      for (int r = 0; r < 4; ++r) {
        const int m = brow + wm * 64 + mi * 16 + (lane >> 4) * 4 + r;
        C[(size_t)m * N + n] = acc[mi][ni][r] * s + b;
      }
    }
}

extern "C" void kernel_launch(void* const* d_in, const int* in_sizes, int n_in,
                              void* d_out, int out_size, void* d_ws, size_t ws_size,
                              hipStream_t stream) {
  const float* x    = (const float*)d_in[0];   // [M][K] fp32
  const float* w    = (const float*)d_in[1];   // [N][K] fp32
  const float* bias = (const float*)d_in[2];   // [N]    fp32
  float* out = (float*)d_out;                  // [M][N] fp32

  const int O = in_sizes[2];                   // 4096 out_features
  const int K = in_sizes[1] / O;               // 4096 in_features
  const int M = in_sizes[0] / K;               // 8192 tokens

  // ws layout: [0..255] scales, qx (i8), qw (i8), partials (2*NB floats)
  unsigned* scales = (unsigned*)d_ws;
  signed char* qx = (signed char*)d_ws + 256;
  signed char* qw = qx + (size_t)M * K;
  float* partials = (float*)(qw + (size_t)O * K);
  // needs 256 + M*K + O*K + 8*NB_QA bytes ≈ 50.3 MB of ws

  int n4x = M * K / 4, n4w = O * K / 4;
  const float4* x4 = (const float4*)x;
  const float4* w4 = (const float4*)w;
  unsigned* qxu = (unsigned*)qx;
  unsigned* qwu = (unsigned*)qw;

  void* args[] = { (void*)&x4, (void*)&qxu, (void*)&n4x,
                   (void*)&w4, (void*)&qwu, (void*)&n4w,
                   (void*)&partials, (void*)&scales };
  hipLaunchCooperativeKernel((const void*)k_quantabs,
                             dim3(NB_QA), dim3(256), args, 0, stream);

  const int grid = (M / BM) * (O / BN);        // 64 * 32 = 2048
  k_gemm<<<grid, 256, 0, stream>>>(qx, qw, bias, scales, out, M, O, K);
}